// Round 4
// baseline (227.017 us; speedup 1.0000x reference)
//
#include <hip/hip_runtime.h>

typedef unsigned short u16;
typedef unsigned int   u32;
typedef __attribute__((ext_vector_type(8))) short bf16x8;
typedef __attribute__((ext_vector_type(4))) float f32x4;

#define MFMA16(a,b,c) __builtin_amdgcn_mfma_f32_16x16x32_bf16((a),(b),(c),0,0,0)
#define QSCALE 0.1803368801111204f   // 0.125 * log2(e)

__device__ __forceinline__ u16 f2bf(float f){
  u32 u = __builtin_bit_cast(u32, f);
  u32 r = u + 0x7fffu + ((u>>16)&1u);
  return (u16)(r>>16);
}
__device__ __forceinline__ float bf2f(u16 h){
  return __builtin_bit_cast(float, (u32)h<<16);
}

union V8 { u16 s[8]; uint4 v; };

// ---- merged conversions: hs (3072 blocks) + 4 weights (4*288 blocks) ----
__global__ __launch_bounds__(256) void cvt_all(const float* __restrict__ hs,
    const float* __restrict__ Wq, const float* __restrict__ Wk,
    const float* __restrict__ Wv, const float* __restrict__ Wo,
    u16* __restrict__ hsb, u16* __restrict__ wqkv,
    u16* __restrict__ woh, u16* __restrict__ wol)
{
  const int bid = blockIdx.x;
  if (bid < 3072){
    int i = bid*256 + threadIdx.x;
    const float4* p = (const float4*)(hs + (size_t)i*8);
    float4 a = p[0], b = p[1];
    V8 t;
    t.s[0]=f2bf(a.x); t.s[1]=f2bf(a.y); t.s[2]=f2bf(a.z); t.s[3]=f2bf(a.w);
    t.s[4]=f2bf(b.x); t.s[5]=f2bf(b.y); t.s[6]=f2bf(b.z); t.s[7]=f2bf(b.w);
    *(uint4*)(hsb + (size_t)i*8) = t.v;
    return;
  }
  const int r = bid - 3072;
  const int seg = r / 288;
  const int off = (r - seg*288)*256 + threadIdx.x;
  const float* src = seg==0?Wq: seg==1?Wk: seg==2?Wv: Wo;
  const float4* p = (const float4*)(src + (size_t)off*8);
  float4 a = p[0], b = p[1];
  float xs[8] = {a.x,a.y,a.z,a.w,b.x,b.y,b.z,b.w};
  if (seg < 3){
    V8 t;
    #pragma unroll
    for (int j=0;j<8;++j) t.s[j]=f2bf(xs[j]);
    *(uint4*)(wqkv + (size_t)seg*589824 + (size_t)off*8) = t.v;
  } else {
    V8 th, tl;
    #pragma unroll
    for (int j=0;j<8;++j){
      u16 hh = f2bf(xs[j]);
      th.s[j] = hh;
      tl.s[j] = f2bf(xs[j] - bf2f(hh));
    }
    *(uint4*)(woh + (size_t)off*8) = th.v;
    *(uint4*)(wol + (size_t)off*8) = tl.v;
  }
}

// ---- fused QKV GEMM: [8192x768] @ [2304x768]^T ----
__global__ __launch_bounds__(256) void mm_qkv(const u16* __restrict__ A, const u16* __restrict__ Bp,
    const float* __restrict__ bq, const float* __restrict__ bk, const float* __restrict__ bvv,
    u16* __restrict__ Oq, u16* __restrict__ Ok, u16* __restrict__ Ov)
{
  __shared__ u16 As[128*64], Bs[128*64];
  const int bid = blockIdx.x;                 // 1152
  const int sid = (bid & 7)*144 + (bid >> 3); // XCD swizzle
  const int mb = sid/18, nb = sid - mb*18;
  const int m0 = mb*128, n0 = nb*128;
  const int tid = threadIdx.x;
  const int lane = tid&63, wid = tid>>6;
  const int wr = wid>>1, wc = wid&1;
  const int fr = lane&15, fg = lane>>4;
  f32x4 zz = {0.f,0.f,0.f,0.f};
  f32x4 acc[4][4];
  #pragma unroll
  for (int i=0;i<4;++i)
    #pragma unroll
    for (int j=0;j<4;++j) acc[i][j]=zz;

  for (int k0=0;k0<768;k0+=64){
    __syncthreads();
    #pragma unroll
    for (int c=0;c<4;++c){
      int e=(c*256+tid)*8; int row=e>>6, col=e&63;
      int sidx=(row*64+col)^((row&7)<<3);
      *(uint4*)&As[sidx] = *(const uint4*)&A[(size_t)(m0+row)*768 + k0+col];
      *(uint4*)&Bs[sidx] = *(const uint4*)&Bp[(size_t)(n0+row)*768 + k0+col];
    }
    __syncthreads();
    #pragma unroll
    for (int ks=0;ks<2;++ks){
      bf16x8 bfr[4];
      #pragma unroll
      for (int nt=0;nt<4;++nt){
        int rowb = wc*64+nt*16+fr;
        bfr[nt] = *(const bf16x8*)&Bs[(rowb*64 + ks*32 + fg*8)^((rowb&7)<<3)];
      }
      #pragma unroll
      for (int mt=0;mt<4;++mt){
        int rowa = wr*64+mt*16+fr;
        bf16x8 af = *(const bf16x8*)&As[(rowa*64 + ks*32 + fg*8)^((rowa&7)<<3)];
        #pragma unroll
        for (int nt=0;nt<4;++nt)
          acc[mt][nt] = MFMA16(af, bfr[nt], acc[mt][nt]);
      }
    }
  }
  const int seg = nb/6;                         // 0=q 1=k 2=v
  const float* bias = seg==0?bq: seg==1?bk:bvv;
  u16* O = seg==0?Oq: seg==1?Ok:Ov;
  const float sc = (seg==0) ? QSCALE : 1.0f;
  #pragma unroll
  for (int mt=0;mt<4;++mt){
    #pragma unroll
    for (int nt=0;nt<4;++nt){
      int colb = n0 + wc*64 + nt*16 + fr;
      int colw = colb - seg*768;
      float bz = bias[colw];
      int hh = colw>>6, d = colw&63;
      #pragma unroll
      for (int rr=0;rr<4;++rr){
        int row = m0 + wr*64 + mt*16 + fg*4 + rr;
        int b = row>>10, nn = row&1023;
        float v = (acc[mt][nt][rr] + bz) * sc;
        size_t oi;
        if (seg < 2) oi = ((size_t)(b*12+hh)<<16) + (size_t)nn*64 + d;
        else         oi = ((size_t)(b*12+hh)<<16) + (size_t)d*1024 + nn;
        O[oi] = f2bf(v);
      }
    }
  }
}

// ---- split (hi/lo) 3-product GEMM: fp32 out + bias ----
__global__ __launch_bounds__(256) void mm_split(const u16* __restrict__ Ahg, const u16* __restrict__ Alg,
                                                const u16* __restrict__ Bhg, const u16* __restrict__ Blg,
                                                const float* __restrict__ bias, float* __restrict__ O)
{
  __shared__ u16 Ahs[128*64], Als[128*64], Bhs[128*64], Bls[128*64];
  const int bid = blockIdx.x;                 // 384
  const int sid = (bid & 7)*48 + (bid >> 3);
  const int mb = sid/6, nb = sid - mb*6;
  const int m0 = mb*128, n0 = nb*128;
  const int tid = threadIdx.x;
  const int lane = tid&63, wid = tid>>6;
  const int wr = wid>>1, wc = wid&1;
  const int fr = lane&15, fg = lane>>4;
  f32x4 zz = {0.f,0.f,0.f,0.f};
  f32x4 acc[4][4];
  #pragma unroll
  for (int i=0;i<4;++i)
    #pragma unroll
    for (int j=0;j<4;++j) acc[i][j]=zz;

  for (int k0=0;k0<768;k0+=64){
    __syncthreads();
    #pragma unroll
    for (int c=0;c<4;++c){
      int e=(c*256+tid)*8; int row=e>>6, col=e&63;
      int sidx=(row*64+col)^((row&7)<<3);
      size_t ga=(size_t)(m0+row)*768 + k0+col;
      size_t gb=(size_t)(n0+row)*768 + k0+col;
      *(uint4*)&Ahs[sidx] = *(const uint4*)&Ahg[ga];
      *(uint4*)&Als[sidx] = *(const uint4*)&Alg[ga];
      *(uint4*)&Bhs[sidx] = *(const uint4*)&Bhg[gb];
      *(uint4*)&Bls[sidx] = *(const uint4*)&Blg[gb];
    }
    __syncthreads();
    #pragma unroll
    for (int ks=0;ks<2;++ks){
      bf16x8 bh4[4], bl4[4];
      #pragma unroll
      for (int nt=0;nt<4;++nt){
        int rowb = wc*64+nt*16+fr;
        int idx = (rowb*64 + ks*32 + fg*8)^((rowb&7)<<3);
        bh4[nt] = *(const bf16x8*)&Bhs[idx];
        bl4[nt] = *(const bf16x8*)&Bls[idx];
      }
      #pragma unroll
      for (int mt=0;mt<4;++mt){
        int rowa = wr*64+mt*16+fr;
        int idx = (rowa*64 + ks*32 + fg*8)^((rowa&7)<<3);
        bf16x8 ah = *(const bf16x8*)&Ahs[idx];
        bf16x8 al = *(const bf16x8*)&Als[idx];
        #pragma unroll
        for (int nt=0;nt<4;++nt){
          acc[mt][nt] = MFMA16(ah, bh4[nt], acc[mt][nt]);
          acc[mt][nt] = MFMA16(ah, bl4[nt], acc[mt][nt]);
          acc[mt][nt] = MFMA16(al, bh4[nt], acc[mt][nt]);
        }
      }
    }
  }
  #pragma unroll
  for (int mt=0;mt<4;++mt){
    #pragma unroll
    for (int nt=0;nt<4;++nt){
      int colb = n0 + wc*64 + nt*16 + fr;
      float bz = bias[colb];
      #pragma unroll
      for (int rr=0;rr<4;++rr){
        int row = m0 + wr*64 + mt*16 + fg*4 + rr;
        O[(size_t)row*768 + colb] = acc[mt][nt][rr] + bz;
      }
    }
  }
}

// ---- MFMA flash attention: K register double-buffer, early V loads ----
// grid (96, 8): blockIdx.x = bh so same-head q-tiles share an XCD
__global__ __launch_bounds__(256, 3) void attn(const u16* __restrict__ qh, const u16* __restrict__ kh,
                                               const u16* __restrict__ vh,
                                               u16* __restrict__ ch, u16* __restrict__ cl)
{
  __shared__ u16 Ps[4][32][72];
  const int tid=threadIdx.x, w=tid>>6, lane=tid&63;
  const int fr=lane&15, fg=lane>>4;
  const int bh=blockIdx.x, qt=blockIdx.y;
  const size_t base=(size_t)bh<<16;
  const int q0=qt*128 + w*32;
  const u16* kptr = kh + base;
  const u16* vptr = vh + base;   // [bh][d][n]

  bf16x8 qf[2][2];
  #pragma unroll
  for (int mt=0;mt<2;++mt)
    #pragma unroll
    for (int ks=0;ks<2;++ks)
      qf[mt][ks] = *(const bf16x8*)&qh[base + (size_t)(q0+mt*16+fr)*64 + ks*32 + fg*8];

  f32x4 zz = {0.f,0.f,0.f,0.f};
  f32x4 o[2][4];
  float lr[2][4];
  #pragma unroll
  for (int mt=0;mt<2;++mt)
    #pragma unroll
    for (int j=0;j<4;++j){ o[mt][j]=zz; lr[mt][j]=0.f; }

  bf16x8 kbuf[2][8];
  #pragma unroll
  for (int ct=0;ct<4;++ct)
    #pragma unroll
    for (int ks=0;ks<2;++ks)
      kbuf[0][ct*2+ks] = *(const bf16x8*)&kptr[(size_t)(ct*16+fr)*64 + ks*32 + fg*8];

  for (int kt2=0; kt2<8; ++kt2){
    #pragma unroll
    for (int p=0; p<2; ++p){
      const int kt  = kt2*2 + p;
      const int ktn = (kt+1) & 15;
      // prefetch next K tile into the other buffer
      #pragma unroll
      for (int ct=0;ct<4;++ct)
        #pragma unroll
        for (int ks=0;ks<2;++ks)
          kbuf[p^1][ct*2+ks] = *(const bf16x8*)&kptr[(size_t)(ktn*64+ct*16+fr)*64 + ks*32 + fg*8];

      // QK^T with current K
      f32x4 s[2][4];
      #pragma unroll
      for (int mt=0;mt<2;++mt)
        #pragma unroll
        for (int j=0;j<4;++j) s[mt][j]=zz;
      __builtin_amdgcn_s_setprio(1);
      #pragma unroll
      for (int ct=0;ct<4;++ct)
        #pragma unroll
        for (int ks=0;ks<2;++ks){
          s[0][ct]=MFMA16(qf[0][ks], kbuf[p][ct*2+ks], s[0][ct]);
          s[1][ct]=MFMA16(qf[1][ks], kbuf[p][ct*2+ks], s[1][ct]);
        }
      __builtin_amdgcn_s_setprio(0);

      // V loads for this kt (issued before softmax so exp covers latency)
      bf16x8 vf[2][4];
      #pragma unroll
      for (int ks2=0;ks2<2;++ks2)
        #pragma unroll
        for (int dt=0;dt<4;++dt)
          vf[ks2][dt] = *(const bf16x8*)&vptr[(size_t)(dt*16+fr)*1024 + kt*64 + ks2*32 + fg*8];

      // softmax: p = exp2(s) (Q pre-scaled by 0.125*log2e), bf16-truncated;
      // l sums the SAME truncated values so the bias cancels in the ratio
      #pragma unroll
      for (int mt=0;mt<2;++mt){
        #pragma unroll
        for (int rr=0;rr<4;++rr){
          int qr = mt*16+fg*4+rr;
          float acc_l = 0.f;
          #pragma unroll
          for (int ct=0;ct<4;++ct){
            float e = __builtin_amdgcn_exp2f(s[mt][ct][rr]);
            u32 u = __builtin_bit_cast(u32, e);
            acc_l += __builtin_bit_cast(float, u & 0xffff0000u);
            Ps[w][qr][ct*16+fr] = (u16)(u>>16);
          }
          lr[mt][rr] += acc_l;
        }
      }

      // PV
      __builtin_amdgcn_s_setprio(1);
      #pragma unroll
      for (int ks2=0;ks2<2;++ks2){
        #pragma unroll
        for (int mt=0;mt<2;++mt){
          bf16x8 pa = *(const bf16x8*)&Ps[w][mt*16+fr][ks2*32+fg*8];
          #pragma unroll
          for (int dt=0;dt<4;++dt)
            o[mt][dt]=MFMA16(pa, vf[ks2][dt], o[mt][dt]);
        }
      }
      __builtin_amdgcn_s_setprio(0);
    }
  }

  float inv[2][4];
  #pragma unroll
  for (int mt=0;mt<2;++mt)
    #pragma unroll
    for (int rr=0;rr<4;++rr){
      float l = lr[mt][rr];
      l += __shfl_xor(l,1); l += __shfl_xor(l,2);
      l += __shfl_xor(l,4); l += __shfl_xor(l,8);
      inv[mt][rr] = 1.0f / l;
    }
  const int b=bh/12, hd=bh%12;
  #pragma unroll
  for (int mt=0;mt<2;++mt){
    #pragma unroll
    for (int dt=0;dt<4;++dt){
      int d = dt*16 + fr;
      #pragma unroll
      for (int rr=0;rr<4;++rr){
        int n = q0 + mt*16 + fg*4 + rr;
        float val = o[mt][dt][rr] * inv[mt][rr];
        size_t oi = ((size_t)b*1024 + n)*768 + hd*64 + d;
        u16 hv = f2bf(val);
        ch[oi]=hv;
        cl[oi]=f2bf(val - bf2f(hv));
      }
    }
  }
}

extern "C" void kernel_launch(void* const* d_in, const int* in_sizes, int n_in,
                              void* d_out, int out_size, void* d_ws, size_t ws_size,
                              hipStream_t stream) {
  const float* hs = (const float*)d_in[0];
  const float* Wq = (const float*)d_in[1];
  const float* bq = (const float*)d_in[2];
  const float* Wk = (const float*)d_in[3];
  const float* bk = (const float*)d_in[4];
  const float* Wv = (const float*)d_in[5];
  const float* bv = (const float*)d_in[6];
  const float* Wo = (const float*)d_in[7];
  const float* bo = (const float*)d_in[8];
  float* out = (float*)d_out;

  const size_t PS = (size_t)8192*768;
  u16* ws16  = (u16*)d_ws;
  u16* hs_bf = ws16;
  u16* q_bf  = ws16 + PS;
  u16* k_bf  = ws16 + 2*PS;
  u16* v_bf  = ws16 + 3*PS;                 // transposed per head [bh][d][n]
  u16* c_lo  = ws16 + 4*PS;
  u16* wqkv  = ws16 + 5*PS;
  u16* woh   = wqkv + 3*589824;
  u16* wol   = woh + 589824;
  u16* c_hi  = hs_bf;

  dim3 blk(256);
  cvt_all<<<3072 + 4*288, blk, 0, stream>>>(hs, Wq, Wk, Wv, Wo, hs_bf, wqkv, woh, wol);
  mm_qkv<<<1152, blk, 0, stream>>>(hs_bf, wqkv, bq, bk, bv, q_bf, k_bf, v_bf);
  attn<<<dim3(96,8), blk, 0, stream>>>(q_bf, k_bf, v_bf, c_hi, c_lo);
  mm_split<<<384, blk, 0, stream>>>(c_hi, c_lo, woh, wol, bo, out);
}

// Round 5
// 156.776 us; speedup vs baseline: 1.4480x; 1.4480x over previous
//
#include <hip/hip_runtime.h>

typedef unsigned short u16;
typedef unsigned int   u32;
typedef __attribute__((ext_vector_type(8))) short bf16x8;
typedef __attribute__((ext_vector_type(4))) float f32x4;
typedef __attribute__((address_space(3))) u32 lds_u32;
typedef __attribute__((address_space(1))) u32 gbl_u32;

#define MFMA16(a,b,c) __builtin_amdgcn_mfma_f32_16x16x32_bf16((a),(b),(c),0,0,0)
#define QSCALE 0.1803368801111204f   // 0.125 * log2(e)

__device__ __forceinline__ u16 f2bf(float f){
  u32 u = __builtin_bit_cast(u32, f);
  u32 r = u + 0x7fffu + ((u>>16)&1u);
  return (u16)(r>>16);
}
__device__ __forceinline__ float bf2f(u16 h){
  return __builtin_bit_cast(float, (u32)h<<16);
}

union V8 { u16 s[8]; uint4 v; };

// ---- merged conversions: hs (3072 blocks) + 4 weights (4*288 blocks) ----
__global__ __launch_bounds__(256) void cvt_all(const float* __restrict__ hs,
    const float* __restrict__ Wq, const float* __restrict__ Wk,
    const float* __restrict__ Wv, const float* __restrict__ Wo,
    u16* __restrict__ hsb, u16* __restrict__ wqkv,
    u16* __restrict__ woh, u16* __restrict__ wol)
{
  const int bid = blockIdx.x;
  if (bid < 3072){
    int i = bid*256 + threadIdx.x;
    const float4* p = (const float4*)(hs + (size_t)i*8);
    float4 a = p[0], b = p[1];
    V8 t;
    t.s[0]=f2bf(a.x); t.s[1]=f2bf(a.y); t.s[2]=f2bf(a.z); t.s[3]=f2bf(a.w);
    t.s[4]=f2bf(b.x); t.s[5]=f2bf(b.y); t.s[6]=f2bf(b.z); t.s[7]=f2bf(b.w);
    *(uint4*)(hsb + (size_t)i*8) = t.v;
    return;
  }
  const int r = bid - 3072;
  const int seg = r / 288;
  const int off = (r - seg*288)*256 + threadIdx.x;
  const float* src = seg==0?Wq: seg==1?Wk: seg==2?Wv: Wo;
  const float4* p = (const float4*)(src + (size_t)off*8);
  float4 a = p[0], b = p[1];
  float xs[8] = {a.x,a.y,a.z,a.w,b.x,b.y,b.z,b.w};
  if (seg < 3){
    V8 t;
    #pragma unroll
    for (int j=0;j<8;++j) t.s[j]=f2bf(xs[j]);
    *(uint4*)(wqkv + (size_t)seg*589824 + (size_t)off*8) = t.v;
  } else {
    V8 th, tl;
    #pragma unroll
    for (int j=0;j<8;++j){
      u16 hh = f2bf(xs[j]);
      th.s[j] = hh;
      tl.s[j] = f2bf(xs[j] - bf2f(hh));
    }
    *(uint4*)(woh + (size_t)off*8) = th.v;
    *(uint4*)(wol + (size_t)off*8) = tl.v;
  }
}

// ---- fused QKV GEMM: [8192x768] @ [2304x768]^T ----
__global__ __launch_bounds__(256) void mm_qkv(const u16* __restrict__ A, const u16* __restrict__ Bp,
    const float* __restrict__ bq, const float* __restrict__ bk, const float* __restrict__ bvv,
    u16* __restrict__ Oq, u16* __restrict__ Ok, u16* __restrict__ Ov)
{
  __shared__ u16 As[128*64], Bs[128*64];
  const int bid = blockIdx.x;                 // 1152
  const int sid = (bid & 7)*144 + (bid >> 3); // XCD swizzle
  const int mb = sid/18, nb = sid - mb*18;
  const int m0 = mb*128, n0 = nb*128;
  const int tid = threadIdx.x;
  const int lane = tid&63, wid = tid>>6;
  const int wr = wid>>1, wc = wid&1;
  const int fr = lane&15, fg = lane>>4;
  f32x4 zz = {0.f,0.f,0.f,0.f};
  f32x4 acc[4][4];
  #pragma unroll
  for (int i=0;i<4;++i)
    #pragma unroll
    for (int j=0;j<4;++j) acc[i][j]=zz;

  for (int k0=0;k0<768;k0+=64){
    __syncthreads();
    #pragma unroll
    for (int c=0;c<4;++c){
      int e=(c*256+tid)*8; int row=e>>6, col=e&63;
      int sidx=(row*64+col)^((row&7)<<3);
      *(uint4*)&As[sidx] = *(const uint4*)&A[(size_t)(m0+row)*768 + k0+col];
      *(uint4*)&Bs[sidx] = *(const uint4*)&Bp[(size_t)(n0+row)*768 + k0+col];
    }
    __syncthreads();
    #pragma unroll
    for (int ks=0;ks<2;++ks){
      bf16x8 bfr[4];
      #pragma unroll
      for (int nt=0;nt<4;++nt){
        int rowb = wc*64+nt*16+fr;
        bfr[nt] = *(const bf16x8*)&Bs[(rowb*64 + ks*32 + fg*8)^((rowb&7)<<3)];
      }
      #pragma unroll
      for (int mt=0;mt<4;++mt){
        int rowa = wr*64+mt*16+fr;
        bf16x8 af = *(const bf16x8*)&As[(rowa*64 + ks*32 + fg*8)^((rowa&7)<<3)];
        #pragma unroll
        for (int nt=0;nt<4;++nt)
          acc[mt][nt] = MFMA16(af, bfr[nt], acc[mt][nt]);
      }
    }
  }
  const int seg = nb/6;                         // 0=q 1=k 2=v
  const float* bias = seg==0?bq: seg==1?bk:bvv;
  u16* O = seg==0?Oq: seg==1?Ok:Ov;
  const float sc = (seg==0) ? QSCALE : 1.0f;
  #pragma unroll
  for (int mt=0;mt<4;++mt){
    #pragma unroll
    for (int nt=0;nt<4;++nt){
      int colb = n0 + wc*64 + nt*16 + fr;
      int colw = colb - seg*768;
      float bz = bias[colw];
      int hh = colw>>6, d = colw&63;
      #pragma unroll
      for (int rr=0;rr<4;++rr){
        int row = m0 + wr*64 + mt*16 + fg*4 + rr;
        int b = row>>10, nn = row&1023;
        float v = (acc[mt][nt][rr] + bz) * sc;
        size_t oi;
        if (seg < 2) oi = ((size_t)(b*12+hh)<<16) + (size_t)nn*64 + d;
        else         oi = ((size_t)(b*12+hh)<<16) + (size_t)d*1024 + nn;
        O[oi] = f2bf(v);
      }
    }
  }
}

// ---- split (hi/lo) 3-product GEMM: fp32 out + bias ----
__global__ __launch_bounds__(256) void mm_split(const u16* __restrict__ Ahg, const u16* __restrict__ Alg,
                                                const u16* __restrict__ Bhg, const u16* __restrict__ Blg,
                                                const float* __restrict__ bias, float* __restrict__ O)
{
  __shared__ u16 Ahs[128*64], Als[128*64], Bhs[128*64], Bls[128*64];
  const int bid = blockIdx.x;                 // 384
  const int sid = (bid & 7)*48 + (bid >> 3);
  const int mb = sid/6, nb = sid - mb*6;
  const int m0 = mb*128, n0 = nb*128;
  const int tid = threadIdx.x;
  const int lane = tid&63, wid = tid>>6;
  const int wr = wid>>1, wc = wid&1;
  const int fr = lane&15, fg = lane>>4;
  f32x4 zz = {0.f,0.f,0.f,0.f};
  f32x4 acc[4][4];
  #pragma unroll
  for (int i=0;i<4;++i)
    #pragma unroll
    for (int j=0;j<4;++j) acc[i][j]=zz;

  for (int k0=0;k0<768;k0+=64){
    __syncthreads();
    #pragma unroll
    for (int c=0;c<4;++c){
      int e=(c*256+tid)*8; int row=e>>6, col=e&63;
      int sidx=(row*64+col)^((row&7)<<3);
      size_t ga=(size_t)(m0+row)*768 + k0+col;
      size_t gb=(size_t)(n0+row)*768 + k0+col;
      *(uint4*)&Ahs[sidx] = *(const uint4*)&Ahg[ga];
      *(uint4*)&Als[sidx] = *(const uint4*)&Alg[ga];
      *(uint4*)&Bhs[sidx] = *(const uint4*)&Bhg[gb];
      *(uint4*)&Bls[sidx] = *(const uint4*)&Blg[gb];
    }
    __syncthreads();
    #pragma unroll
    for (int ks=0;ks<2;++ks){
      bf16x8 bh4[4], bl4[4];
      #pragma unroll
      for (int nt=0;nt<4;++nt){
        int rowb = wc*64+nt*16+fr;
        int idx = (rowb*64 + ks*32 + fg*8)^((rowb&7)<<3);
        bh4[nt] = *(const bf16x8*)&Bhs[idx];
        bl4[nt] = *(const bf16x8*)&Bls[idx];
      }
      #pragma unroll
      for (int mt=0;mt<4;++mt){
        int rowa = wr*64+mt*16+fr;
        int idx = (rowa*64 + ks*32 + fg*8)^((rowa&7)<<3);
        bf16x8 ah = *(const bf16x8*)&Ahs[idx];
        bf16x8 al = *(const bf16x8*)&Als[idx];
        #pragma unroll
        for (int nt=0;nt<4;++nt){
          acc[mt][nt] = MFMA16(ah, bh4[nt], acc[mt][nt]);
          acc[mt][nt] = MFMA16(ah, bl4[nt], acc[mt][nt]);
          acc[mt][nt] = MFMA16(al, bh4[nt], acc[mt][nt]);
        }
      }
    }
  }
  #pragma unroll
  for (int mt=0;mt<4;++mt){
    #pragma unroll
    for (int nt=0;nt<4;++nt){
      int colb = n0 + wc*64 + nt*16 + fr;
      float bz = bias[colb];
      #pragma unroll
      for (int rr=0;rr<4;++rr){
        int row = m0 + wr*64 + mt*16 + fg*4 + rr;
        O[(size_t)row*768 + colb] = acc[mt][nt][rr] + bz;
      }
    }
  }
}

// ---- MFMA flash attention: async LDS double-buffered K/V (global_load_lds) ----
// grid (96, 8): blockIdx.x = bh so same-head q-tiles share an XCD.
// LDS tiles are XOR-swizzled via pre-swizzled GLOBAL source (linear LDS dest);
// readers apply byte ^ ((row&7)<<4); since row&7 == fr&7 the XOR is a per-thread const.
__global__ __launch_bounds__(256) void attn(const u16* __restrict__ qh, const u16* __restrict__ kh,
                                            const u16* __restrict__ vh,
                                            u16* __restrict__ ch, u16* __restrict__ cl)
{
  __shared__ u16 Kb[2][4096];   // 8KB per buf: 64 keys x 64 d
  __shared__ u16 Vb[2][4096];   // 8KB per buf: 64 d-rows x 64 keys
  __shared__ u16 Ps[4][32][72];
  const int tid=threadIdx.x, w=tid>>6, lane=tid&63;
  const int fr=lane&15, fg=lane>>4;
  const int bh=blockIdx.x, qt=blockIdx.y;
  const size_t base=(size_t)bh<<16;
  const int q0=qt*128 + w*32;

  const char* kbase = (const char*)(kh + base);          // [1024 keys][64 d], 128B rows
  const char* vbase = (const char*)(vh + base);          // [64 d][1024 n], 2KB rows

  // per-thread stage source offsets: chunk ci = c*256+tid -> LDS byte ci*16 (linear)
  int koff[2], voff[2];
  #pragma unroll
  for (int c=0;c<2;++c){
    int ci = c*256 + tid;
    int row = ci>>3;
    int colp = ((ci&7)*16) ^ ((row&7)<<4);
    koff[c] = row*128  + colp;
    voff[c] = row*2048 + colp;
  }

  // Q fragments in registers (Q pre-scaled by QSCALE in mm_qkv)
  bf16x8 qf[2][2];
  #pragma unroll
  for (int mt=0;mt<2;++mt)
    #pragma unroll
    for (int ks=0;ks<2;++ks)
      qf[mt][ks] = *(const bf16x8*)&qh[base + (size_t)(q0+mt*16+fr)*64 + ks*32 + fg*8];

  // reader constants: byte = ct*2048 + fr*128 + lowK[ks]  (XOR folded, carry-free)
  const int swz = (fr&7)<<4;
  int lowD[2];
  #pragma unroll
  for (int ks=0;ks<2;++ks) lowD[ks] = (ks*64 + fg*16) ^ swz;
  const int frbase = fr*128;

  f32x4 zz = {0.f,0.f,0.f,0.f};
  f32x4 o[2][4];
  float lr[2][4];
  #pragma unroll
  for (int mt=0;mt<2;++mt)
    #pragma unroll
    for (int j=0;j<4;++j){ o[mt][j]=zz; lr[mt][j]=0.f; }

  // prologue: stage tile 0 into buf 0
  {
    const char* kt_ = kbase;
    const char* vt_ = vbase;
    #pragma unroll
    for (int c=0;c<2;++c){
      __builtin_amdgcn_global_load_lds((const gbl_u32*)(kt_ + koff[c]),
        (lds_u32*)((char*)&Kb[0][0] + c*4096 + w*1024), 16, 0, 0);
      __builtin_amdgcn_global_load_lds((const gbl_u32*)(vt_ + voff[c]),
        (lds_u32*)((char*)&Vb[0][0] + c*4096 + w*1024), 16, 0, 0);
    }
  }
  __syncthreads();

  for (int kt=0; kt<16; ++kt){
    const int buf = kt & 1;
    // stage next tile into other buffer (async; drained by end-of-iter barrier)
    {
      const int ktn = (kt+1) & 15;
      const char* kt_ = kbase + ktn*8192;
      const char* vt_ = vbase + ktn*128;
      #pragma unroll
      for (int c=0;c<2;++c){
        __builtin_amdgcn_global_load_lds((const gbl_u32*)(kt_ + koff[c]),
          (lds_u32*)((char*)&Kb[buf^1][0] + c*4096 + w*1024), 16, 0, 0);
        __builtin_amdgcn_global_load_lds((const gbl_u32*)(vt_ + voff[c]),
          (lds_u32*)((char*)&Vb[buf^1][0] + c*4096 + w*1024), 16, 0, 0);
      }
    }

    // QK^T from LDS
    f32x4 s[2][4];
    #pragma unroll
    for (int mt=0;mt<2;++mt)
      #pragma unroll
      for (int j=0;j<4;++j) s[mt][j]=zz;
    const char* kb = (const char*)&Kb[buf][0];
    __builtin_amdgcn_s_setprio(1);
    #pragma unroll
    for (int ct=0;ct<4;++ct){
      #pragma unroll
      for (int ks=0;ks<2;++ks){
        bf16x8 kf = *(const bf16x8*)(kb + ct*2048 + frbase + lowD[ks]);
        s[0][ct]=MFMA16(qf[0][ks],kf,s[0][ct]);
        s[1][ct]=MFMA16(qf[1][ks],kf,s[1][ct]);
      }
    }
    __builtin_amdgcn_s_setprio(0);

    // softmax: p = exp2(s), bf16-truncated; l sums the SAME truncated values
    #pragma unroll
    for (int mt=0;mt<2;++mt){
      #pragma unroll
      for (int rr=0;rr<4;++rr){
        int qr = mt*16+fg*4+rr;
        float acc_l = 0.f;
        #pragma unroll
        for (int ct=0;ct<4;++ct){
          float e = __builtin_amdgcn_exp2f(s[mt][ct][rr]);
          u32 u = __builtin_bit_cast(u32, e);
          acc_l += __builtin_bit_cast(float, u & 0xffff0000u);
          Ps[w][qr][ct*16+fr] = (u16)(u>>16);
        }
        lr[mt][rr] += acc_l;
      }
    }

    // PV from LDS
    const char* vb = (const char*)&Vb[buf][0];
    __builtin_amdgcn_s_setprio(1);
    #pragma unroll
    for (int ks2=0;ks2<2;++ks2){
      bf16x8 vf[4];
      #pragma unroll
      for (int dt=0;dt<4;++dt)
        vf[dt] = *(const bf16x8*)(vb + dt*2048 + frbase + lowD[ks2]);
      #pragma unroll
      for (int mt=0;mt<2;++mt){
        bf16x8 pa = *(const bf16x8*)&Ps[w][mt*16+fr][ks2*32+fg*8];
        #pragma unroll
        for (int dt=0;dt<4;++dt)
          o[mt][dt]=MFMA16(pa, vf[dt], o[mt][dt]);
      }
    }
    __builtin_amdgcn_s_setprio(0);

    __syncthreads();   // drains vmcnt (stage of kt+1, covered by compute) + swaps buffers
  }

  float inv[2][4];
  #pragma unroll
  for (int mt=0;mt<2;++mt)
    #pragma unroll
    for (int rr=0;rr<4;++rr){
      float l = lr[mt][rr];
      l += __shfl_xor(l,1); l += __shfl_xor(l,2);
      l += __shfl_xor(l,4); l += __shfl_xor(l,8);
      inv[mt][rr] = 1.0f / l;
    }
  const int b=bh/12, hd=bh%12;
  #pragma unroll
  for (int mt=0;mt<2;++mt){
    #pragma unroll
    for (int dt=0;dt<4;++dt){
      int d = dt*16 + fr;
      #pragma unroll
      for (int rr=0;rr<4;++rr){
        int n = q0 + mt*16 + fg*4 + rr;
        float val = o[mt][dt][rr] * inv[mt][rr];
        size_t oi = ((size_t)b*1024 + n)*768 + hd*64 + d;
        u16 hv = f2bf(val);
        ch[oi]=hv;
        cl[oi]=f2bf(val - bf2f(hv));
      }
    }
  }
}

extern "C" void kernel_launch(void* const* d_in, const int* in_sizes, int n_in,
                              void* d_out, int out_size, void* d_ws, size_t ws_size,
                              hipStream_t stream) {
  const float* hs = (const float*)d_in[0];
  const float* Wq = (const float*)d_in[1];
  const float* bq = (const float*)d_in[2];
  const float* Wk = (const float*)d_in[3];
  const float* bk = (const float*)d_in[4];
  const float* Wv = (const float*)d_in[5];
  const float* bv = (const float*)d_in[6];
  const float* Wo = (const float*)d_in[7];
  const float* bo = (const float*)d_in[8];
  float* out = (float*)d_out;

  const size_t PS = (size_t)8192*768;
  u16* ws16  = (u16*)d_ws;
  u16* hs_bf = ws16;
  u16* q_bf  = ws16 + PS;
  u16* k_bf  = ws16 + 2*PS;
  u16* v_bf  = ws16 + 3*PS;                 // transposed per head [bh][d][n]
  u16* c_lo  = ws16 + 4*PS;
  u16* wqkv  = ws16 + 5*PS;
  u16* woh   = wqkv + 3*589824;
  u16* wol   = woh + 589824;
  u16* c_hi  = hs_bf;

  dim3 blk(256);
  cvt_all<<<3072 + 4*288, blk, 0, stream>>>(hs, Wq, Wk, Wv, Wo, hs_bf, wqkv, woh, wol);
  mm_qkv<<<1152, blk, 0, stream>>>(hs_bf, wqkv, bq, bk, bv, q_bf, k_bf, v_bf);
  attn<<<dim3(96,8), blk, 0, stream>>>(q_bf, k_bf, v_bf, c_hi, c_lo);
  mm_split<<<384, blk, 0, stream>>>(c_hi, c_lo, woh, wol, bo, out);
}

// Round 6
// 148.481 us; speedup vs baseline: 1.5289x; 1.0559x over previous
//
#include <hip/hip_runtime.h>

typedef unsigned short u16;
typedef unsigned int   u32;
typedef __attribute__((ext_vector_type(8))) short bf16x8;
typedef __attribute__((ext_vector_type(4))) float f32x4;
typedef __attribute__((address_space(3))) u32 lds_u32;
typedef __attribute__((address_space(1))) u32 gbl_u32;

#define MFMA16(a,b,c) __builtin_amdgcn_mfma_f32_16x16x32_bf16((a),(b),(c),0,0,0)
#define QSCALE 0.1803368801111204f   // 0.125 * log2(e)

__device__ __forceinline__ u16 f2bf(float f){
  u32 u = __builtin_bit_cast(u32, f);
  u32 r = u + 0x7fffu + ((u>>16)&1u);
  return (u16)(r>>16);
}
__device__ __forceinline__ float bf2f(u16 h){
  return __builtin_bit_cast(float, (u32)h<<16);
}

union V8 { u16 s[8]; uint4 v; };

// ---- merged conversions: hs (3072 blocks) + 4 weights (4*288 blocks) ----
__global__ __launch_bounds__(256) void cvt_all(const float* __restrict__ hs,
    const float* __restrict__ Wq, const float* __restrict__ Wk,
    const float* __restrict__ Wv, const float* __restrict__ Wo,
    u16* __restrict__ hsb, u16* __restrict__ wqkv,
    u16* __restrict__ woh, u16* __restrict__ wol)
{
  const int bid = blockIdx.x;
  if (bid < 3072){
    int i = bid*256 + threadIdx.x;
    const float4* p = (const float4*)(hs + (size_t)i*8);
    float4 a = p[0], b = p[1];
    V8 t;
    t.s[0]=f2bf(a.x); t.s[1]=f2bf(a.y); t.s[2]=f2bf(a.z); t.s[3]=f2bf(a.w);
    t.s[4]=f2bf(b.x); t.s[5]=f2bf(b.y); t.s[6]=f2bf(b.z); t.s[7]=f2bf(b.w);
    *(uint4*)(hsb + (size_t)i*8) = t.v;
    return;
  }
  const int r = bid - 3072;
  const int seg = r / 288;
  const int off = (r - seg*288)*256 + threadIdx.x;
  const float* src = seg==0?Wq: seg==1?Wk: seg==2?Wv: Wo;
  const float4* p = (const float4*)(src + (size_t)off*8);
  float4 a = p[0], b = p[1];
  float xs[8] = {a.x,a.y,a.z,a.w,b.x,b.y,b.z,b.w};
  if (seg < 3){
    V8 t;
    #pragma unroll
    for (int j=0;j<8;++j) t.s[j]=f2bf(xs[j]);
    *(uint4*)(wqkv + (size_t)seg*589824 + (size_t)off*8) = t.v;
  } else {
    V8 th, tl;
    #pragma unroll
    for (int j=0;j<8;++j){
      u16 hh = f2bf(xs[j]);
      th.s[j] = hh;
      tl.s[j] = f2bf(xs[j] - bf2f(hh));
    }
    *(uint4*)(woh + (size_t)off*8) = th.v;
    *(uint4*)(wol + (size_t)off*8) = tl.v;
  }
}

// ---- fused QKV GEMM (m97 structure): global_load_lds staging, 128x128 tile, BK=64 ----
// LDS linear; global source pre-swizzled col^((row&7)<<4); readers fold the XOR.
__global__ __launch_bounds__(256) void mm_qkv(const u16* __restrict__ A, const u16* __restrict__ Bp,
    const float* __restrict__ bq, const float* __restrict__ bk, const float* __restrict__ bvv,
    u16* __restrict__ Oq, u16* __restrict__ Ok, u16* __restrict__ Ov)
{
  __shared__ u16 As[128*64], Bs[128*64];
  const int bid = blockIdx.x;                 // 1152
  const int sid = (bid & 7)*144 + (bid >> 3); // XCD swizzle
  const int mb = sid/18, nb = sid - mb*18;
  const int m0 = mb*128, n0 = nb*128;
  const int tid = threadIdx.x;
  const int lane = tid&63, wid = tid>>6;
  const int wr = wid>>1, wc = wid&1;
  const int fr = lane&15, fg = lane>>4;

  const char* Ab = (const char*)A;
  const char* Bb = (const char*)Bp;
  size_t asrc[4], bsrc[4];
  #pragma unroll
  for (int c=0;c<4;++c){
    int ci = c*256 + tid;
    int row = ci>>3, colp = (ci&7)*16;
    int scol = colp ^ ((row&7)<<4);
    asrc[c] = (size_t)(m0+row)*1536 + scol;
    bsrc[c] = (size_t)(n0+row)*1536 + scol;
  }
  const int swz = (fr&7)<<4;
  int lowD[2];
  #pragma unroll
  for (int ks=0;ks<2;++ks) lowD[ks] = (ks*64 + fg*16) ^ swz;

  f32x4 zz = {0.f,0.f,0.f,0.f};
  f32x4 acc[4][4];
  #pragma unroll
  for (int i=0;i<4;++i)
    #pragma unroll
    for (int j=0;j<4;++j) acc[i][j]=zz;

  for (int k0=0;k0<768;k0+=64){
    __syncthreads();
    #pragma unroll
    for (int c=0;c<4;++c){
      __builtin_amdgcn_global_load_lds((const gbl_u32*)(Ab + asrc[c] + k0*2),
        (lds_u32*)((char*)As + c*4096 + wid*1024), 16, 0, 0);
      __builtin_amdgcn_global_load_lds((const gbl_u32*)(Bb + bsrc[c] + k0*2),
        (lds_u32*)((char*)Bs + c*4096 + wid*1024), 16, 0, 0);
    }
    __syncthreads();
    #pragma unroll
    for (int ks=0;ks<2;++ks){
      bf16x8 bfr[4];
      #pragma unroll
      for (int nt=0;nt<4;++nt)
        bfr[nt] = *(const bf16x8*)((const char*)Bs + (wc*64+nt*16+fr)*128 + lowD[ks]);
      #pragma unroll
      for (int mt=0;mt<4;++mt){
        bf16x8 af = *(const bf16x8*)((const char*)As + (wr*64+mt*16+fr)*128 + lowD[ks]);
        #pragma unroll
        for (int nt=0;nt<4;++nt)
          acc[mt][nt] = MFMA16(af, bfr[nt], acc[mt][nt]);
      }
    }
  }
  const int seg = nb/6;                         // 0=q 1=k 2=v
  const float* bias = seg==0?bq: seg==1?bk:bvv;
  u16* O = seg==0?Oq: seg==1?Ok:Ov;
  const float sc = (seg==0) ? QSCALE : 1.0f;
  #pragma unroll
  for (int mt=0;mt<4;++mt){
    #pragma unroll
    for (int nt=0;nt<4;++nt){
      int colb = n0 + wc*64 + nt*16 + fr;
      int colw = colb - seg*768;
      float bz = bias[colw];
      int hh = colw>>6, d = colw&63;
      #pragma unroll
      for (int rr=0;rr<4;++rr){
        int row = m0 + wr*64 + mt*16 + fg*4 + rr;
        int b = row>>10, nn = row&1023;
        float v = (acc[mt][nt][rr] + bz) * sc;
        size_t oi;
        if (seg < 2) oi = ((size_t)(b*12+hh)<<16) + (size_t)nn*64 + d;
        else         oi = ((size_t)(b*12+hh)<<16) + (size_t)d*1024 + nn;
        O[oi] = f2bf(v);
      }
    }
  }
}

// ---- split (hi/lo) 3-product GEMM, global_load_lds staging ----
__global__ __launch_bounds__(256) void mm_split(const u16* __restrict__ Ahg, const u16* __restrict__ Alg,
                                                const u16* __restrict__ Bhg, const u16* __restrict__ Blg,
                                                const float* __restrict__ bias, float* __restrict__ O)
{
  __shared__ u16 Ahs[128*64], Als[128*64], Bhs[128*64], Bls[128*64];
  const int bid = blockIdx.x;                 // 384
  const int sid = (bid & 7)*48 + (bid >> 3);
  const int mb = sid/6, nb = sid - mb*6;
  const int m0 = mb*128, n0 = nb*128;
  const int tid = threadIdx.x;
  const int lane = tid&63, wid = tid>>6;
  const int wr = wid>>1, wc = wid&1;
  const int fr = lane&15, fg = lane>>4;

  const char* Ahb = (const char*)Ahg;
  const char* Alb = (const char*)Alg;
  const char* Bhb = (const char*)Bhg;
  const char* Blb = (const char*)Blg;
  size_t asrc[4], bsrc[4];
  #pragma unroll
  for (int c=0;c<4;++c){
    int ci = c*256 + tid;
    int row = ci>>3, colp = (ci&7)*16;
    int scol = colp ^ ((row&7)<<4);
    asrc[c] = (size_t)(m0+row)*1536 + scol;
    bsrc[c] = (size_t)(n0+row)*1536 + scol;
  }
  const int swz = (fr&7)<<4;
  int lowD[2];
  #pragma unroll
  for (int ks=0;ks<2;++ks) lowD[ks] = (ks*64 + fg*16) ^ swz;

  f32x4 zz = {0.f,0.f,0.f,0.f};
  f32x4 acc[4][4];
  #pragma unroll
  for (int i=0;i<4;++i)
    #pragma unroll
    for (int j=0;j<4;++j) acc[i][j]=zz;

  for (int k0=0;k0<768;k0+=64){
    __syncthreads();
    #pragma unroll
    for (int c=0;c<4;++c){
      __builtin_amdgcn_global_load_lds((const gbl_u32*)(Ahb + asrc[c] + k0*2),
        (lds_u32*)((char*)Ahs + c*4096 + wid*1024), 16, 0, 0);
      __builtin_amdgcn_global_load_lds((const gbl_u32*)(Alb + asrc[c] + k0*2),
        (lds_u32*)((char*)Als + c*4096 + wid*1024), 16, 0, 0);
      __builtin_amdgcn_global_load_lds((const gbl_u32*)(Bhb + bsrc[c] + k0*2),
        (lds_u32*)((char*)Bhs + c*4096 + wid*1024), 16, 0, 0);
      __builtin_amdgcn_global_load_lds((const gbl_u32*)(Blb + bsrc[c] + k0*2),
        (lds_u32*)((char*)Bls + c*4096 + wid*1024), 16, 0, 0);
    }
    __syncthreads();
    #pragma unroll
    for (int ks=0;ks<2;++ks){
      bf16x8 bh4[4], bl4[4];
      #pragma unroll
      for (int nt=0;nt<4;++nt){
        int boff = (wc*64+nt*16+fr)*128 + lowD[ks];
        bh4[nt] = *(const bf16x8*)((const char*)Bhs + boff);
        bl4[nt] = *(const bf16x8*)((const char*)Bls + boff);
      }
      #pragma unroll
      for (int mt=0;mt<4;++mt){
        int aoff = (wr*64+mt*16+fr)*128 + lowD[ks];
        bf16x8 ah = *(const bf16x8*)((const char*)Ahs + aoff);
        bf16x8 al = *(const bf16x8*)((const char*)Als + aoff);
        #pragma unroll
        for (int nt=0;nt<4;++nt){
          acc[mt][nt] = MFMA16(ah, bh4[nt], acc[mt][nt]);
          acc[mt][nt] = MFMA16(ah, bl4[nt], acc[mt][nt]);
          acc[mt][nt] = MFMA16(al, bh4[nt], acc[mt][nt]);
        }
      }
    }
  }
  #pragma unroll
  for (int mt=0;mt<4;++mt){
    #pragma unroll
    for (int nt=0;nt<4;++nt){
      int colb = n0 + wc*64 + nt*16 + fr;
      float bz = bias[colb];
      #pragma unroll
      for (int rr=0;rr<4;++rr){
        int row = m0 + wr*64 + mt*16 + fg*4 + rr;
        O[(size_t)row*768 + colb] = acc[mt][nt][rr] + bz;
      }
    }
  }
}

// ---- MFMA flash attention: async LDS double-buffered K/V (unchanged from r5) ----
__global__ __launch_bounds__(256) void attn(const u16* __restrict__ qh, const u16* __restrict__ kh,
                                            const u16* __restrict__ vh,
                                            u16* __restrict__ ch, u16* __restrict__ cl)
{
  __shared__ u16 Kb[2][4096];
  __shared__ u16 Vb[2][4096];
  __shared__ u16 Ps[4][32][72];
  const int tid=threadIdx.x, w=tid>>6, lane=tid&63;
  const int fr=lane&15, fg=lane>>4;
  const int bh=blockIdx.x, qt=blockIdx.y;
  const size_t base=(size_t)bh<<16;
  const int q0=qt*128 + w*32;

  const char* kbase = (const char*)(kh + base);
  const char* vbase = (const char*)(vh + base);

  int koff[2], voff[2];
  #pragma unroll
  for (int c=0;c<2;++c){
    int ci = c*256 + tid;
    int row = ci>>3;
    int colp = ((ci&7)*16) ^ ((row&7)<<4);
    koff[c] = row*128  + colp;
    voff[c] = row*2048 + colp;
  }

  bf16x8 qf[2][2];
  #pragma unroll
  for (int mt=0;mt<2;++mt)
    #pragma unroll
    for (int ks=0;ks<2;++ks)
      qf[mt][ks] = *(const bf16x8*)&qh[base + (size_t)(q0+mt*16+fr)*64 + ks*32 + fg*8];

  const int swz = (fr&7)<<4;
  int lowD[2];
  #pragma unroll
  for (int ks=0;ks<2;++ks) lowD[ks] = (ks*64 + fg*16) ^ swz;
  const int frbase = fr*128;

  f32x4 zz = {0.f,0.f,0.f,0.f};
  f32x4 o[2][4];
  float lr[2][4];
  #pragma unroll
  for (int mt=0;mt<2;++mt)
    #pragma unroll
    for (int j=0;j<4;++j){ o[mt][j]=zz; lr[mt][j]=0.f; }

  {
    #pragma unroll
    for (int c=0;c<2;++c){
      __builtin_amdgcn_global_load_lds((const gbl_u32*)(kbase + koff[c]),
        (lds_u32*)((char*)&Kb[0][0] + c*4096 + w*1024), 16, 0, 0);
      __builtin_amdgcn_global_load_lds((const gbl_u32*)(vbase + voff[c]),
        (lds_u32*)((char*)&Vb[0][0] + c*4096 + w*1024), 16, 0, 0);
    }
  }
  __syncthreads();

  for (int kt=0; kt<16; ++kt){
    const int buf = kt & 1;
    {
      const int ktn = (kt+1) & 15;
      const char* kt_ = kbase + ktn*8192;
      const char* vt_ = vbase + ktn*128;
      #pragma unroll
      for (int c=0;c<2;++c){
        __builtin_amdgcn_global_load_lds((const gbl_u32*)(kt_ + koff[c]),
          (lds_u32*)((char*)&Kb[buf^1][0] + c*4096 + w*1024), 16, 0, 0);
        __builtin_amdgcn_global_load_lds((const gbl_u32*)(vt_ + voff[c]),
          (lds_u32*)((char*)&Vb[buf^1][0] + c*4096 + w*1024), 16, 0, 0);
      }
    }

    f32x4 s[2][4];
    #pragma unroll
    for (int mt=0;mt<2;++mt)
      #pragma unroll
      for (int j=0;j<4;++j) s[mt][j]=zz;
    const char* kb = (const char*)&Kb[buf][0];
    __builtin_amdgcn_s_setprio(1);
    #pragma unroll
    for (int ct=0;ct<4;++ct){
      #pragma unroll
      for (int ks=0;ks<2;++ks){
        bf16x8 kf = *(const bf16x8*)(kb + ct*2048 + frbase + lowD[ks]);
        s[0][ct]=MFMA16(qf[0][ks],kf,s[0][ct]);
        s[1][ct]=MFMA16(qf[1][ks],kf,s[1][ct]);
      }
    }
    __builtin_amdgcn_s_setprio(0);

    #pragma unroll
    for (int mt=0;mt<2;++mt){
      #pragma unroll
      for (int rr=0;rr<4;++rr){
        int qr = mt*16+fg*4+rr;
        float acc_l = 0.f;
        #pragma unroll
        for (int ct=0;ct<4;++ct){
          float e = __builtin_amdgcn_exp2f(s[mt][ct][rr]);
          u32 u = __builtin_bit_cast(u32, e);
          acc_l += __builtin_bit_cast(float, u & 0xffff0000u);
          Ps[w][qr][ct*16+fr] = (u16)(u>>16);
        }
        lr[mt][rr] += acc_l;
      }
    }

    const char* vb = (const char*)&Vb[buf][0];
    __builtin_amdgcn_s_setprio(1);
    #pragma unroll
    for (int ks2=0;ks2<2;++ks2){
      bf16x8 vf[4];
      #pragma unroll
      for (int dt=0;dt<4;++dt)
        vf[dt] = *(const bf16x8*)(vb + dt*2048 + frbase + lowD[ks2]);
      #pragma unroll
      for (int mt=0;mt<2;++mt){
        bf16x8 pa = *(const bf16x8*)&Ps[w][mt*16+fr][ks2*32+fg*8];
        #pragma unroll
        for (int dt=0;dt<4;++dt)
          o[mt][dt]=MFMA16(pa, vf[dt], o[mt][dt]);
      }
    }
    __builtin_amdgcn_s_setprio(0);

    __syncthreads();
  }

  float inv[2][4];
  #pragma unroll
  for (int mt=0;mt<2;++mt)
    #pragma unroll
    for (int rr=0;rr<4;++rr){
      float l = lr[mt][rr];
      l += __shfl_xor(l,1); l += __shfl_xor(l,2);
      l += __shfl_xor(l,4); l += __shfl_xor(l,8);
      inv[mt][rr] = 1.0f / l;
    }
  const int b=bh/12, hd=bh%12;
  #pragma unroll
  for (int mt=0;mt<2;++mt){
    #pragma unroll
    for (int dt=0;dt<4;++dt){
      int d = dt*16 + fr;
      #pragma unroll
      for (int rr=0;rr<4;++rr){
        int n = q0 + mt*16 + fg*4 + rr;
        float val = o[mt][dt][rr] * inv[mt][rr];
        size_t oi = ((size_t)b*1024 + n)*768 + hd*64 + d;
        u16 hv = f2bf(val);
        ch[oi]=hv;
        cl[oi]=f2bf(val - bf2f(hv));
      }
    }
  }
}

extern "C" void kernel_launch(void* const* d_in, const int* in_sizes, int n_in,
                              void* d_out, int out_size, void* d_ws, size_t ws_size,
                              hipStream_t stream) {
  const float* hs = (const float*)d_in[0];
  const float* Wq = (const float*)d_in[1];
  const float* bq = (const float*)d_in[2];
  const float* Wk = (const float*)d_in[3];
  const float* bk = (const float*)d_in[4];
  const float* Wv = (const float*)d_in[5];
  const float* bv = (const float*)d_in[6];
  const float* Wo = (const float*)d_in[7];
  const float* bo = (const float*)d_in[8];
  float* out = (float*)d_out;

  const size_t PS = (size_t)8192*768;
  u16* ws16  = (u16*)d_ws;
  u16* hs_bf = ws16;
  u16* q_bf  = ws16 + PS;
  u16* k_bf  = ws16 + 2*PS;
  u16* v_bf  = ws16 + 3*PS;                 // transposed per head [bh][d][n]
  u16* c_lo  = ws16 + 4*PS;
  u16* wqkv  = ws16 + 5*PS;
  u16* woh   = wqkv + 3*589824;
  u16* wol   = woh + 589824;
  u16* c_hi  = hs_bf;

  dim3 blk(256);
  cvt_all<<<3072 + 4*288, blk, 0, stream>>>(hs, Wq, Wk, Wv, Wo, hs_bf, wqkv, woh, wol);
  mm_qkv<<<1152, blk, 0, stream>>>(hs_bf, wqkv, bq, bk, bv, q_bf, k_bf, v_bf);
  attn<<<dim3(96,8), blk, 0, stream>>>(q_bf, k_bf, v_bf, c_hi, c_lo);
  mm_split<<<384, blk, 0, stream>>>(c_hi, c_lo, woh, wol, bo, out);
}